// Round 3
// baseline (67.106 us; speedup 1.0000x reference)
//
#include <hip/hip_runtime.h>

#define SDF_THR 5e-5f
#define TRACE_ITERS 10
#define N_STEPS 100
#define N_ROOTFIND 8

// correctly-rounded k/99.0f (Markstein 2-fma refinement); constant-folds for literal k
__device__ __forceinline__ float div99(int k) {
    const float c = 1.0f / 99.0f;
    float fk = (float)k;
    float t0 = fk * c;
    float e  = fmaf(t0, -99.0f, fk);
    return fmaf(e, c, t0);
}

// sdf(cam + a*ray) with |ray|=1:  q(a) = a^2 + 2a*rcd + cam2
__device__ __forceinline__ float sdfq(float a, float trcd, float cam2) {
    float q = fmaf(a, a + trcd, cam2);
    return sqrtf(fmaxf(q, 0.0f)) - 1.0f;
}

// ---------------- Kernel A: intersect + sphere-trace + compact unf rays ----------------
__global__ __launch_bounds__(256) void trace_kernel(
    const float* __restrict__ cam, const float* __restrict__ ray,
    float* __restrict__ out,
    int* __restrict__ wl_cnt, int* __restrict__ wl_gid,
    float* __restrict__ wl_smin, float* __restrict__ wl_smax,
    int N, int R)
{
    int gid = blockIdx.x * blockDim.x + threadIdx.x;
    if (gid >= R) return;
    int b = gid / N;

    float cx = cam[b * 3 + 0], cy = cam[b * 3 + 1], cz = cam[b * 3 + 2];
    float rx = ray[(size_t)gid * 3 + 0], ry = ray[(size_t)gid * 3 + 1], rz = ray[(size_t)gid * 3 + 2];

    float rcd  = rx * cx + ry * cy + rz * cz;
    float cam2 = cx * cx + cy * cy + cz * cz;
    float trcd = rcd + rcd;

    // sphere intersections (OBJ_R = 5)
    float under = rcd * rcd - (cam2 - 25.0f);
    bool  m0 = under > 0.0f;
    float sq = sqrtf(m0 ? under : 1.0f);
    float nearv = m0 ? fmaxf(-sq - rcd, 0.0f) : 0.0f;
    float farv  = m0 ? fmaxf( sq - rcd, 0.0f) : 0.0f;

    bool  unf_s = m0, unf_e = m0;
    float acc_s = nearv, acc_e = farv;
    // unmasked next is bit-identical downstream: dead lanes have cur==0 everywhere
    float next_s = sdfq(acc_s, trcd, cam2);
    float next_e = sdfq(acc_e, trcd, cam2);

    #pragma unroll 1
    for (int i = 0; i < TRACE_ITERS; ++i) {
        bool gs = next_s > SDF_THR, ge = next_e > SDF_THR;
        float cur_s = (unf_s && gs) ? next_s : 0.0f;
        float cur_e = (unf_e && ge) ? next_e : 0.0f;
        unf_s = unf_s && gs;
        unf_e = unf_e && ge;
        acc_s += cur_s;
        acc_e -= cur_e;
        next_s = sdfq(acc_s, trcd, cam2);
        next_e = sdfq(acc_e, trcd, cam2);
        bool np_s = (next_s < 0.0f) || (rcd + acc_s > 0.0f);  // ray.pts = rcd + acc
        bool np_e = (next_e < 0.0f) || (rcd + acc_e < 0.0f);
        // line-search back-off (step 0.9); no-op for dead lanes (cur==0)
        acc_s = np_s ? fmaf(-0.9f, cur_s, acc_s) : acc_s;
        acc_e = np_e ? fmaf( 0.9f, cur_e, acc_e) : acc_e;
        next_s = sdfq(acc_s, trcd, cam2);   // idempotent when !np (acc unchanged)
        next_e = sdfq(acc_e, trcd, cam2);
        bool lt = acc_s < acc_e;
        unf_s = unf_s && lt;
        unf_e = unf_e && lt;
    }
    unf_s = unf_s && (next_s > SDF_THR);    // final mask refresh

    // default outputs (overwritten by sampler for unf rays)
    out[(size_t)gid * 3 + 0] = fmaf(acc_s, rx, cx);
    out[(size_t)gid * 3 + 1] = fmaf(acc_s, ry, cy);
    out[(size_t)gid * 3 + 2] = fmaf(acc_s, rz, cz);
    out[(size_t)R * 3 + gid] = (acc_s < acc_e) ? 1.0f : 0.0f;
    out[(size_t)R * 4 + gid] = acc_s;

    // wave-aggregated worklist append
    unsigned long long mask = __ballot(unf_s);
    if (mask != 0ull) {
        int lane = threadIdx.x & 63;
        int base = 0;
        if (lane == 0) base = atomicAdd(wl_cnt, (int)__popcll(mask));
        base = __builtin_amdgcn_readfirstlane(base);
        if (unf_s) {
            int slot = base + (int)__popcll(mask & ((1ull << lane) - 1ull));
            wl_gid[slot]  = gid;
            wl_smin[slot] = acc_s;
            wl_smax[slot] = acc_e;
        }
    }
}

// ---------------- Kernel B: dense ray sampler over the worklist ----------------
__global__ __launch_bounds__(256) void sample_kernel(
    const float* __restrict__ cam, const float* __restrict__ ray,
    float* __restrict__ out,
    const int* __restrict__ wl_cnt, const int* __restrict__ wl_gid,
    const float* __restrict__ wl_smin, const float* __restrict__ wl_smax,
    int N, int R)
{
    int i = blockIdx.x * blockDim.x + threadIdx.x;
    if (i >= wl_cnt[0]) return;
    int gid = wl_gid[i];
    float smin = wl_smin[i], smax = wl_smax[i];
    int b = gid / N;

    float cx = cam[b * 3 + 0], cy = cam[b * 3 + 1], cz = cam[b * 3 + 2];
    float rx = ray[(size_t)gid * 3 + 0], ry = ray[(size_t)gid * 3 + 1], rz = ray[(size_t)gid * 3 + 2];
    float rcd  = rx * cx + ry * cy + rz * cz;
    float cam2 = cx * cx + cy * cy + cz * cz;
    float trcd = rcd + rcd;
    float dzr  = smax - smin;

    // 4 independent accumulator chains (ILP); first-occurrence via (q,k) lexicographic
    float qmin[4] = {3.4e38f, 3.4e38f, 3.4e38f, 3.4e38f};
    float fkq[4]  = {0.0f, 0.0f, 0.0f, 0.0f};
    float fneg[4] = {1e9f, 1e9f, 1e9f, 1e9f};

    #pragma unroll
    for (int k = 0; k < N_STEPS; ++k) {
        int j = k & 3;
        float z = fmaf(div99(k), dzr, smin);      // div99(k) folds to a constant
        float q = fmaf(z, z + trcd, cam2);
        float fk = (float)k;
        fneg[j] = fminf(fneg[j], (q < 1.0f) ? fk : 1e9f);
        if (q < qmin[j]) { qmin[j] = q; fkq[j] = fk; }
    }

    float kneg_f = fminf(fminf(fneg[0], fneg[1]), fminf(fneg[2], fneg[3]));
    float bq = qmin[0], bk = fkq[0];
    #pragma unroll
    for (int j = 1; j < 4; ++j) {
        bool better = (qmin[j] < bq) || ((qmin[j] == bq) && (fkq[j] < bk));
        bq = better ? qmin[j] : bq;
        bk = better ? fkq[j]  : bk;
    }

    float out_d;
    bool  out_m;
    if (kneg_f < 1e8f) {
        // bisection between samples kneg-1 and kneg (z recomputed bit-identically)
        int kneg = (int)kneg_f;
        int klo  = (kneg - 1 > 0) ? (kneg - 1) : 0;
        float lo = fmaf(div99(klo),  dzr, smin);
        float hi = fmaf(div99(kneg), dzr, smin);
        #pragma unroll
        for (int it = 0; it < N_ROOTFIND; ++it) {
            float mid = 0.5f * (lo + hi);
            float qm  = fmaf(mid, mid + trcd, cam2);
            bool go_lo = qm > 1.0f;
            lo = go_lo ? mid : lo;
            hi = go_lo ? hi : mid;
        }
        out_d = 0.5f * (lo + hi);
        out_m = true;
    } else {
        out_d = fmaf(div99((int)bk), dzr, smin);  // min-sdf sample
        out_m = false;
    }

    out[(size_t)gid * 3 + 0] = fmaf(out_d, rx, cx);
    out[(size_t)gid * 3 + 1] = fmaf(out_d, ry, cy);
    out[(size_t)gid * 3 + 2] = fmaf(out_d, rz, cz);
    out[(size_t)R * 3 + gid] = out_m ? 1.0f : 0.0f;
    out[(size_t)R * 4 + gid] = out_d;
}

// ---------------- Fallback: single-kernel (round-2) path if ws too small ----------------
__global__ __launch_bounds__(256) void raytrace_mono_kernel(
    const float* __restrict__ cam, const float* __restrict__ ray,
    float* __restrict__ out, int N, int R)
{
    int gid = blockIdx.x * blockDim.x + threadIdx.x;
    if (gid >= R) return;
    int b = gid / N;
    float cx = cam[b*3+0], cy = cam[b*3+1], cz = cam[b*3+2];
    float rx = ray[(size_t)gid*3+0], ry = ray[(size_t)gid*3+1], rz = ray[(size_t)gid*3+2];
    float rcd = rx*cx + ry*cy + rz*cz;
    float cam2 = cx*cx + cy*cy + cz*cz;
    float trcd = rcd + rcd;
    float under = rcd*rcd - (cam2 - 25.0f);
    bool m0 = under > 0.0f;
    float sq = sqrtf(m0 ? under : 1.0f);
    float nearv = m0 ? fmaxf(-sq - rcd, 0.0f) : 0.0f;
    float farv  = m0 ? fmaxf( sq - rcd, 0.0f) : 0.0f;
    bool unf_s = m0, unf_e = m0;
    float acc_s = nearv, acc_e = farv;
    float next_s = unf_s ? sdfq(acc_s, trcd, cam2) : 0.0f;
    float next_e = unf_e ? sdfq(acc_e, trcd, cam2) : 0.0f;
    #pragma unroll 1
    for (int i = 0; i < TRACE_ITERS; ++i) {
        float cur_s = unf_s ? next_s : 0.0f;
        cur_s = (cur_s <= SDF_THR) ? 0.0f : cur_s;
        float cur_e = unf_e ? next_e : 0.0f;
        cur_e = (cur_e <= SDF_THR) ? 0.0f : cur_e;
        unf_s = unf_s && (cur_s > SDF_THR);
        unf_e = unf_e && (cur_e > SDF_THR);
        acc_s += cur_s;
        acc_e -= cur_e;
        next_s = unf_s ? sdfq(acc_s, trcd, cam2) : 0.0f;
        next_e = unf_e ? sdfq(acc_e, trcd, cam2) : 0.0f;
        bool np_s = (next_s < 0.0f) || (rcd + acc_s > 0.0f);
        bool np_e = (next_e < 0.0f) || (rcd + acc_e < 0.0f);
        if (np_s) { acc_s -= 0.9f * cur_s; next_s = sdfq(acc_s, trcd, cam2); }
        if (np_e) { acc_e += 0.9f * cur_e; next_e = sdfq(acc_e, trcd, cam2); }
        unf_s = unf_s && (acc_s < acc_e);
        unf_e = unf_e && (acc_s < acc_e);
    }
    { float cur_s = unf_s ? next_s : 0.0f; cur_s = (cur_s <= SDF_THR) ? 0.0f : cur_s; unf_s = unf_s && (cur_s > SDF_THR); }
    bool  out_m = acc_s < acc_e;
    float out_d = acc_s;
    float out_px = fmaf(acc_s, rx, cx), out_py = fmaf(acc_s, ry, cy), out_pz = fmaf(acc_s, rz, cz);
    if (unf_s) {
        float smin = acc_s, dzrl = acc_e - acc_s;
        int kneg = N_STEPS, kqmin = 0;
        float qmin = 3.4e38f;
        #pragma unroll 4
        for (int k = 0; k < N_STEPS; ++k) {
            float z = fmaf(div99(k), dzrl, smin);
            float q = fmaf(z, z + trcd, cam2);
            if (q < 1.0f) kneg = min(kneg, k);
            if (q < qmin) { qmin = q; kqmin = k; }
        }
        if (kneg < N_STEPS) {
            int klo = (kneg - 1 > 0) ? (kneg - 1) : 0;
            float lo = fmaf(div99(klo), dzrl, smin);
            float hi = fmaf(div99(kneg), dzrl, smin);
            #pragma unroll
            for (int it = 0; it < N_ROOTFIND; ++it) {
                float mid = 0.5f * (lo + hi);
                float qm = fmaf(mid, mid + trcd, cam2);
                bool go_lo = qm > 1.0f;
                lo = go_lo ? mid : lo;
                hi = go_lo ? hi : mid;
            }
            float zr = 0.5f * (lo + hi);
            out_d = zr; out_m = true;
            out_px = fmaf(zr, rx, cx); out_py = fmaf(zr, ry, cy); out_pz = fmaf(zr, rz, cz);
        } else {
            float zo = fmaf(div99(kqmin), dzrl, smin);
            out_d = zo; out_m = false;
            out_px = fmaf(zo, rx, cx); out_py = fmaf(zo, ry, cy); out_pz = fmaf(zo, rz, cz);
        }
    }
    out[(size_t)gid*3+0] = out_px;
    out[(size_t)gid*3+1] = out_py;
    out[(size_t)gid*3+2] = out_pz;
    out[(size_t)R*3+gid] = out_m ? 1.0f : 0.0f;
    out[(size_t)R*4+gid] = out_d;
}

extern "C" void kernel_launch(void* const* d_in, const int* in_sizes, int n_in,
                              void* d_out, int out_size, void* d_ws, size_t ws_size,
                              hipStream_t stream) {
    const float* cam = (const float*)d_in[0];
    const float* ray = (const float*)d_in[1];
    int B = in_sizes[0] / 3;
    int R = in_sizes[1] / 3;
    int N = R / B;
    int threads = 256;
    int blocks = (R + threads - 1) / threads;

    size_t needed = 64 + (size_t)R * 12;
    if (ws_size < needed) {
        raytrace_mono_kernel<<<blocks, threads, 0, stream>>>(cam, ray, (float*)d_out, N, R);
        return;
    }

    char* ws = (char*)d_ws;
    int*   wl_cnt  = (int*)ws;
    int*   wl_gid  = (int*)(ws + 64);
    float* wl_smin = (float*)(ws + 64 + (size_t)R * 4);
    float* wl_smax = (float*)(ws + 64 + (size_t)R * 8);

    hipMemsetAsync(d_ws, 0, 64, stream);
    trace_kernel<<<blocks, threads, 0, stream>>>(cam, ray, (float*)d_out,
                                                 wl_cnt, wl_gid, wl_smin, wl_smax, N, R);
    sample_kernel<<<blocks, threads, 0, stream>>>(cam, ray, (float*)d_out,
                                                  wl_cnt, wl_gid, wl_smin, wl_smax, N, R);
}

// Round 4
// 19.823 us; speedup vs baseline: 3.3852x; 3.3852x over previous
//
#include <hip/hip_runtime.h>

#define SDF_THR 5e-5f
#define TRACE_ITERS 10
#define N_STEPS 100
#define N_ROOTFIND 8

// correctly-rounded k/99.0f (Markstein 2-fma refinement); constant-folds for literal k
__device__ __forceinline__ float div99(int k) {
    const float c = 1.0f / 99.0f;
    float fk = (float)k;
    float t0 = fk * c;
    float e  = fmaf(t0, -99.0f, fk);
    return fmaf(e, c, t0);
}

// sdf(cam + a*ray) with |ray|=1:  q(a) = a^2 + 2a*rcd + cam2
__device__ __forceinline__ float sdfq(float a, float trcd, float cam2) {
    float q = fmaf(a, a + trcd, cam2);
    return sqrtf(fmaxf(q, 0.0f)) - 1.0f;
}

// ---------------- Kernel A: intersect + sphere-trace + per-block compaction ----------------
__global__ __launch_bounds__(256) void trace_kernel(
    const float* __restrict__ cam, const float* __restrict__ ray,
    float* __restrict__ out,
    int* __restrict__ wl_cnt, int* __restrict__ wl_gid,
    float* __restrict__ wl_smin, float* __restrict__ wl_smax,
    float* __restrict__ wl_rcd,
    int N, int R)
{
    __shared__ int wcnt[4];
    __shared__ int wbase[4];

    int tid = threadIdx.x;
    int gid = blockIdx.x * 256 + tid;
    bool active = gid < R;
    int g = active ? gid : (R - 1);      // clamp for safe loads; masked below
    int b = g / N;

    float cx = cam[b * 3 + 0], cy = cam[b * 3 + 1], cz = cam[b * 3 + 2];
    float rx = ray[(size_t)g * 3 + 0], ry = ray[(size_t)g * 3 + 1], rz = ray[(size_t)g * 3 + 2];

    float rcd  = rx * cx + ry * cy + rz * cz;
    float cam2 = cx * cx + cy * cy + cz * cz;
    float trcd = rcd + rcd;

    // sphere intersections (OBJ_R = 5)
    float under = rcd * rcd - (cam2 - 25.0f);
    bool  m0 = under > 0.0f;
    float sq = sqrtf(m0 ? under : 1.0f);
    float nearv = m0 ? fmaxf(-sq - rcd, 0.0f) : 0.0f;
    float farv  = m0 ? fmaxf( sq - rcd, 0.0f) : 0.0f;

    // sphere tracing — verbatim round-2 (proven) form
    bool  unf_s = m0, unf_e = m0;
    float acc_s = nearv, acc_e = farv;
    float next_s = unf_s ? sdfq(acc_s, trcd, cam2) : 0.0f;
    float next_e = unf_e ? sdfq(acc_e, trcd, cam2) : 0.0f;

    #pragma unroll 1
    for (int i = 0; i < TRACE_ITERS; ++i) {
        float cur_s = unf_s ? next_s : 0.0f;
        cur_s = (cur_s <= SDF_THR) ? 0.0f : cur_s;
        float cur_e = unf_e ? next_e : 0.0f;
        cur_e = (cur_e <= SDF_THR) ? 0.0f : cur_e;
        unf_s = unf_s && (cur_s > SDF_THR);
        unf_e = unf_e && (cur_e > SDF_THR);
        acc_s += cur_s;
        acc_e -= cur_e;
        next_s = unf_s ? sdfq(acc_s, trcd, cam2) : 0.0f;
        next_e = unf_e ? sdfq(acc_e, trcd, cam2) : 0.0f;
        bool np_s = (next_s < 0.0f) || (rcd + acc_s > 0.0f);   // ray.pts = rcd + acc
        bool np_e = (next_e < 0.0f) || (rcd + acc_e < 0.0f);
        if (np_s) { acc_s -= 0.9f * cur_s; next_s = sdfq(acc_s, trcd, cam2); }
        if (np_e) { acc_e += 0.9f * cur_e; next_e = sdfq(acc_e, trcd, cam2); }
        unf_s = unf_s && (acc_s < acc_e);
        unf_e = unf_e && (acc_s < acc_e);
    }
    // final mask refresh
    {
        float cur_s = unf_s ? next_s : 0.0f;
        cur_s = (cur_s <= SDF_THR) ? 0.0f : cur_s;
        unf_s = unf_s && (cur_s > SDF_THR);
    }
    unf_s = unf_s && active;

    // default outputs (kernel B overwrites unf rays)
    if (active) {
        out[(size_t)gid * 3 + 0] = fmaf(acc_s, rx, cx);
        out[(size_t)gid * 3 + 1] = fmaf(acc_s, ry, cy);
        out[(size_t)gid * 3 + 2] = fmaf(acc_s, rz, cz);
        out[(size_t)R * 3 + gid] = (acc_s < acc_e) ? 1.0f : 0.0f;
        out[(size_t)R * 4 + gid] = acc_s;
    }

    // ---- per-block compaction: ballot + LDS prefix, NO global atomics ----
    unsigned long long mask = __ballot(unf_s);
    int wid = tid >> 6, lane = tid & 63;
    if (lane == 0) wcnt[wid] = (int)__popcll(mask);
    __syncthreads();
    if (tid == 0) {
        int s0 = wcnt[0], s1 = s0 + wcnt[1], s2 = s1 + wcnt[2];
        wbase[0] = 0; wbase[1] = s0; wbase[2] = s1; wbase[3] = s2;
        wl_cnt[blockIdx.x] = s2 + wcnt[3];
    }
    __syncthreads();
    if (unf_s) {
        int slot = blockIdx.x * 256 + wbase[wid]
                 + (int)__popcll(mask & ((1ull << lane) - 1ull));
        wl_gid[slot]  = gid;
        wl_smin[slot] = acc_s;
        wl_smax[slot] = acc_e;
        wl_rcd[slot]  = rcd;
    }
}

// ---------------- Kernel B: dense ray sampler over per-block segments ----------------
__global__ __launch_bounds__(256) void sample_kernel(
    const float* __restrict__ cam, const float* __restrict__ ray,
    float* __restrict__ out,
    const int* __restrict__ wl_cnt, const int* __restrict__ wl_gid,
    const float* __restrict__ wl_smin, const float* __restrict__ wl_smax,
    const float* __restrict__ wl_rcd,
    int N, int R)
{
    int nb = wl_cnt[blockIdx.x];
    int tid = threadIdx.x;
    if (tid >= nb) return;                 // empty waves exit immediately

    int slot = blockIdx.x * 256 + tid;
    int gid  = wl_gid[slot];
    float smin = wl_smin[slot], smax = wl_smax[slot], rcd = wl_rcd[slot];
    int b = gid / N;

    float cx = cam[b * 3 + 0], cy = cam[b * 3 + 1], cz = cam[b * 3 + 2];
    float cam2 = cx * cx + cy * cy + cz * cz;
    float trcd = rcd + rcd;
    float dzr  = smax - smin;

    // 4 independent accumulator chains; first-occurrence via (q,k) lexicographic
    float qmin[4] = {3.4e38f, 3.4e38f, 3.4e38f, 3.4e38f};
    float fkq[4]  = {0.0f, 0.0f, 0.0f, 0.0f};
    float fneg[4] = {1e9f, 1e9f, 1e9f, 1e9f};

    #pragma unroll
    for (int k = 0; k < N_STEPS; ++k) {
        int j = k & 3;
        float z = fmaf(div99(k), dzr, smin);       // div99(k) folds to a constant
        float q = fmaf(z, z + trcd, cam2);
        float fk = (float)k;
        fneg[j] = fminf(fneg[j], (q < 1.0f) ? fk : 1e9f);
        if (q < qmin[j]) { qmin[j] = q; fkq[j] = fk; }
    }

    float kneg_f = fminf(fminf(fneg[0], fneg[1]), fminf(fneg[2], fneg[3]));
    float bq = qmin[0], bk = fkq[0];
    #pragma unroll
    for (int j = 1; j < 4; ++j) {
        bool better = (qmin[j] < bq) || ((qmin[j] == bq) && (fkq[j] < bk));
        bq = better ? qmin[j] : bq;
        bk = better ? fkq[j]  : bk;
    }

    float out_d;
    bool  out_m;
    if (kneg_f < 1e8f) {
        int kneg = (int)kneg_f;
        int klo  = (kneg - 1 > 0) ? (kneg - 1) : 0;
        float lo = fmaf(div99(klo),  dzr, smin);
        float hi = fmaf(div99(kneg), dzr, smin);
        #pragma unroll
        for (int it = 0; it < N_ROOTFIND; ++it) {
            float mid = 0.5f * (lo + hi);
            float qm  = fmaf(mid, mid + trcd, cam2);
            bool go_lo = qm > 1.0f;                 // sdf(mid) > 0
            lo = go_lo ? mid : lo;
            hi = go_lo ? hi : mid;
        }
        out_d = 0.5f * (lo + hi);
        out_m = true;
    } else {
        out_d = fmaf(div99((int)bk), dzr, smin);    // min-sdf sample
        out_m = false;
    }

    float rx = ray[(size_t)gid * 3 + 0], ry = ray[(size_t)gid * 3 + 1], rz = ray[(size_t)gid * 3 + 2];
    out[(size_t)gid * 3 + 0] = fmaf(out_d, rx, cx);
    out[(size_t)gid * 3 + 1] = fmaf(out_d, ry, cy);
    out[(size_t)gid * 3 + 2] = fmaf(out_d, rz, cz);
    out[(size_t)R * 3 + gid] = out_m ? 1.0f : 0.0f;
    out[(size_t)R * 4 + gid] = out_d;
}

// ---------------- Fallback: single-kernel (round-2, 20.5 us) path if ws too small ----------------
__global__ __launch_bounds__(256) void raytrace_mono_kernel(
    const float* __restrict__ cam, const float* __restrict__ ray,
    float* __restrict__ out, int N, int R)
{
    int gid = blockIdx.x * blockDim.x + threadIdx.x;
    if (gid >= R) return;
    int b = gid / N;
    float cx = cam[b*3+0], cy = cam[b*3+1], cz = cam[b*3+2];
    float rx = ray[(size_t)gid*3+0], ry = ray[(size_t)gid*3+1], rz = ray[(size_t)gid*3+2];
    float rcd = rx*cx + ry*cy + rz*cz;
    float cam2 = cx*cx + cy*cy + cz*cz;
    float trcd = rcd + rcd;
    float under = rcd*rcd - (cam2 - 25.0f);
    bool m0 = under > 0.0f;
    float sq = sqrtf(m0 ? under : 1.0f);
    float nearv = m0 ? fmaxf(-sq - rcd, 0.0f) : 0.0f;
    float farv  = m0 ? fmaxf( sq - rcd, 0.0f) : 0.0f;
    bool unf_s = m0, unf_e = m0;
    float acc_s = nearv, acc_e = farv;
    float next_s = unf_s ? sdfq(acc_s, trcd, cam2) : 0.0f;
    float next_e = unf_e ? sdfq(acc_e, trcd, cam2) : 0.0f;
    #pragma unroll 1
    for (int i = 0; i < TRACE_ITERS; ++i) {
        float cur_s = unf_s ? next_s : 0.0f;
        cur_s = (cur_s <= SDF_THR) ? 0.0f : cur_s;
        float cur_e = unf_e ? next_e : 0.0f;
        cur_e = (cur_e <= SDF_THR) ? 0.0f : cur_e;
        unf_s = unf_s && (cur_s > SDF_THR);
        unf_e = unf_e && (cur_e > SDF_THR);
        acc_s += cur_s;
        acc_e -= cur_e;
        next_s = unf_s ? sdfq(acc_s, trcd, cam2) : 0.0f;
        next_e = unf_e ? sdfq(acc_e, trcd, cam2) : 0.0f;
        bool np_s = (next_s < 0.0f) || (rcd + acc_s > 0.0f);
        bool np_e = (next_e < 0.0f) || (rcd + acc_e < 0.0f);
        if (np_s) { acc_s -= 0.9f * cur_s; next_s = sdfq(acc_s, trcd, cam2); }
        if (np_e) { acc_e += 0.9f * cur_e; next_e = sdfq(acc_e, trcd, cam2); }
        unf_s = unf_s && (acc_s < acc_e);
        unf_e = unf_e && (acc_s < acc_e);
    }
    { float cur_s = unf_s ? next_s : 0.0f; cur_s = (cur_s <= SDF_THR) ? 0.0f : cur_s; unf_s = unf_s && (cur_s > SDF_THR); }
    bool  out_m = acc_s < acc_e;
    float out_d = acc_s;
    float out_px = fmaf(acc_s, rx, cx), out_py = fmaf(acc_s, ry, cy), out_pz = fmaf(acc_s, rz, cz);
    if (unf_s) {
        float smin = acc_s, dzrl = acc_e - acc_s;
        int kneg = N_STEPS, kqmin = 0;
        float qmin = 3.4e38f;
        #pragma unroll 4
        for (int k = 0; k < N_STEPS; ++k) {
            float z = fmaf(div99(k), dzrl, smin);
            float q = fmaf(z, z + trcd, cam2);
            if (q < 1.0f) kneg = min(kneg, k);
            if (q < qmin) { qmin = q; kqmin = k; }
        }
        if (kneg < N_STEPS) {
            int klo = (kneg - 1 > 0) ? (kneg - 1) : 0;
            float lo = fmaf(div99(klo), dzrl, smin);
            float hi = fmaf(div99(kneg), dzrl, smin);
            #pragma unroll
            for (int it = 0; it < N_ROOTFIND; ++it) {
                float mid = 0.5f * (lo + hi);
                float qm = fmaf(mid, mid + trcd, cam2);
                bool go_lo = qm > 1.0f;
                lo = go_lo ? mid : lo;
                hi = go_lo ? hi : mid;
            }
            float zr = 0.5f * (lo + hi);
            out_d = zr; out_m = true;
            out_px = fmaf(zr, rx, cx); out_py = fmaf(zr, ry, cy); out_pz = fmaf(zr, rz, cz);
        } else {
            float zo = fmaf(div99(kqmin), dzrl, smin);
            out_d = zo; out_m = false;
            out_px = fmaf(zo, rx, cx); out_py = fmaf(zo, ry, cy); out_pz = fmaf(zo, rz, cz);
        }
    }
    out[(size_t)gid*3+0] = out_px;
    out[(size_t)gid*3+1] = out_py;
    out[(size_t)gid*3+2] = out_pz;
    out[(size_t)R*3+gid] = out_m ? 1.0f : 0.0f;
    out[(size_t)R*4+gid] = out_d;
}

extern "C" void kernel_launch(void* const* d_in, const int* in_sizes, int n_in,
                              void* d_out, int out_size, void* d_ws, size_t ws_size,
                              hipStream_t stream) {
    const float* cam = (const float*)d_in[0];
    const float* ray = (const float*)d_in[1];
    int B = in_sizes[0] / 3;
    int R = in_sizes[1] / 3;
    int N = R / B;
    int threads = 256;
    int blocks = (R + threads - 1) / threads;

    size_t cnt_bytes = ((size_t)blocks * 4 + 63) & ~(size_t)63;
    size_t needed = cnt_bytes + (size_t)R * 16;
    if (ws_size < needed) {
        raytrace_mono_kernel<<<blocks, threads, 0, stream>>>(cam, ray, (float*)d_out, N, R);
        return;
    }

    char* ws = (char*)d_ws;
    int*   wl_cnt  = (int*)ws;
    int*   wl_gid  = (int*)(ws + cnt_bytes);
    float* wl_smin = (float*)(ws + cnt_bytes + (size_t)R * 4);
    float* wl_smax = (float*)(ws + cnt_bytes + (size_t)R * 8);
    float* wl_rcd  = (float*)(ws + cnt_bytes + (size_t)R * 12);

    trace_kernel<<<blocks, threads, 0, stream>>>(cam, ray, (float*)d_out,
                                                 wl_cnt, wl_gid, wl_smin, wl_smax, wl_rcd, N, R);
    sample_kernel<<<blocks, threads, 0, stream>>>(cam, ray, (float*)d_out,
                                                  wl_cnt, wl_gid, wl_smin, wl_smax, wl_rcd, N, R);
}

// Round 5
// 17.050 us; speedup vs baseline: 3.9359x; 1.1627x over previous
//
#include <hip/hip_runtime.h>

#define SDF_THR 5e-5f
#define TRACE_ITERS 10
#define N_STEPS 100
#define N_ROOTFIND 8

// raw v_sqrt_f32 (~1 ulp) — the IEEE sqrtf fixup sequence is ~50 cycles of
// dependent latency and dominates the trace loop's critical path.
__device__ __forceinline__ float fast_sqrtf(float x) {
#if __has_builtin(__builtin_amdgcn_sqrtf)
    return __builtin_amdgcn_sqrtf(x);
#else
    return sqrtf(x);
#endif
}

// correctly-rounded k/99.0f (Markstein 2-fma refinement); constant-folds for literal k
__device__ __forceinline__ float div99(int k) {
    const float c = 1.0f / 99.0f;
    float fk = (float)k;
    float t0 = fk * c;
    float e  = fmaf(t0, -99.0f, fk);
    return fmaf(e, c, t0);
}

// sdf(cam + a*ray) with |ray|=1:  q(a) = a^2 + 2a*rcd + cam2
__device__ __forceinline__ float sdfq(float a, float trcd, float cam2) {
    float q = fmaf(a, a + trcd, cam2);
    return fast_sqrtf(fmaxf(q, 0.0f)) - 1.0f;
}

__global__ __launch_bounds__(256) void raytrace_kernel(
    const float* __restrict__ cam, const float* __restrict__ ray,
    float* __restrict__ out, int N, int R)
{
    int gid = blockIdx.x * blockDim.x + threadIdx.x;
    if (gid >= R) return;
    int b = gid / N;

    float cx = cam[b * 3 + 0], cy = cam[b * 3 + 1], cz = cam[b * 3 + 2];
    float rx = ray[(size_t)gid * 3 + 0], ry = ray[(size_t)gid * 3 + 1], rz = ray[(size_t)gid * 3 + 2];

    float rcd  = rx * cx + ry * cy + rz * cz;
    float cam2 = cx * cx + cy * cy + cz * cz;
    float trcd = rcd + rcd;

    // ---- sphere intersections (OBJ_R = 5); one-time sqrt kept correctly rounded ----
    float under = rcd * rcd - (cam2 - 25.0f);
    bool  m0 = under > 0.0f;
    float sq = sqrtf(m0 ? under : 1.0f);
    float nearv = m0 ? fmaxf(-sq - rcd, 0.0f) : 0.0f;
    float farv  = m0 ? fmaxf( sq - rcd, 0.0f) : 0.0f;

    // ---- sphere tracing (s and e chains are independent -> ILP-2) ----
    bool  unf_s = m0, unf_e = m0;
    float acc_s = nearv, acc_e = farv;
    float next_s = unf_s ? sdfq(acc_s, trcd, cam2) : 0.0f;
    float next_e = unf_e ? sdfq(acc_e, trcd, cam2) : 0.0f;

    #pragma unroll 1
    for (int i = 0; i < TRACE_ITERS; ++i) {
        float cur_s = unf_s ? next_s : 0.0f;
        cur_s = (cur_s <= SDF_THR) ? 0.0f : cur_s;
        float cur_e = unf_e ? next_e : 0.0f;
        cur_e = (cur_e <= SDF_THR) ? 0.0f : cur_e;
        unf_s = unf_s && (cur_s > SDF_THR);
        unf_e = unf_e && (cur_e > SDF_THR);
        acc_s += cur_s;
        acc_e -= cur_e;
        next_s = unf_s ? sdfq(acc_s, trcd, cam2) : 0.0f;
        next_e = unf_e ? sdfq(acc_e, trcd, cam2) : 0.0f;
        bool np_s = (next_s < 0.0f) || (rcd + acc_s > 0.0f);   // ray.pts = rcd + acc
        bool np_e = (next_e < 0.0f) || (rcd + acc_e < 0.0f);
        if (np_s) { acc_s -= 0.9f * cur_s; next_s = sdfq(acc_s, trcd, cam2); }
        if (np_e) { acc_e += 0.9f * cur_e; next_e = sdfq(acc_e, trcd, cam2); }
        unf_s = unf_s && (acc_s < acc_e);
        unf_e = unf_e && (acc_s < acc_e);
        // wave-uniform early exit: converged lanes are provable no-ops (cur==0),
        // so skipping remaining iterations is bit-exact.
        if (!__any(unf_s || unf_e)) break;
    }
    // final mask refresh
    {
        float cur_s = unf_s ? next_s : 0.0f;
        cur_s = (cur_s <= SDF_THR) ? 0.0f : cur_s;
        unf_s = unf_s && (cur_s > SDF_THR);
    }

    // ---- defaults from trace ----
    bool  out_m = acc_s < acc_e;
    float out_d = acc_s;

    if (unf_s) {   // wave-granular skip via execz when no lane is unfinished
        // ---- sampler: decisions on q(z) vs 1; 4 independent accumulator chains ----
        float smin = acc_s, smax = acc_e;
        float dzr = smax - smin;

        float qmin[4] = {3.4e38f, 3.4e38f, 3.4e38f, 3.4e38f};
        float fkq[4]  = {0.0f, 0.0f, 0.0f, 0.0f};
        float fneg[4] = {1e9f, 1e9f, 1e9f, 1e9f};

        #pragma unroll
        for (int k = 0; k < N_STEPS; ++k) {
            int j = k & 3;
            float z = fmaf(div99(k), dzr, smin);     // div99(k) folds to a constant
            float q = fmaf(z, z + trcd, cam2);
            float fk = (float)k;
            fneg[j] = fminf(fneg[j], (q < 1.0f) ? fk : 1e9f);
            if (q < qmin[j]) { qmin[j] = q; fkq[j] = fk; }
        }

        float kneg_f = fminf(fminf(fneg[0], fneg[1]), fminf(fneg[2], fneg[3]));
        float bq = qmin[0], bk = fkq[0];
        #pragma unroll
        for (int j = 1; j < 4; ++j) {
            bool better = (qmin[j] < bq) || ((qmin[j] == bq) && (fkq[j] < bk));
            bq = better ? qmin[j] : bq;
            bk = better ? fkq[j]  : bk;
        }

        if (kneg_f < 1e8f) {
            // bisection between samples kneg-1 and kneg
            int kneg = (int)kneg_f;
            int klo  = (kneg - 1 > 0) ? (kneg - 1) : 0;
            float lo = fmaf(div99(klo),  dzr, smin);
            float hi = fmaf(div99(kneg), dzr, smin);
            #pragma unroll
            for (int it = 0; it < N_ROOTFIND; ++it) {
                float mid = 0.5f * (lo + hi);
                float qm  = fmaf(mid, mid + trcd, cam2);
                bool go_lo = qm > 1.0f;               // sdf(mid) > 0
                lo = go_lo ? mid : lo;
                hi = go_lo ? hi : mid;
            }
            out_d = 0.5f * (lo + hi);
            out_m = true;
        } else {
            out_d = fmaf(div99((int)bk), dzr, smin);  // min-sdf sample
            out_m = false;
        }
    }

    // ---- outputs: pts [R,3] | net_obj [R] | acc_s [R] ----
    out[(size_t)gid * 3 + 0] = fmaf(out_d, rx, cx);
    out[(size_t)gid * 3 + 1] = fmaf(out_d, ry, cy);
    out[(size_t)gid * 3 + 2] = fmaf(out_d, rz, cz);
    out[(size_t)R * 3 + gid] = out_m ? 1.0f : 0.0f;
    out[(size_t)R * 4 + gid] = out_d;
}

extern "C" void kernel_launch(void* const* d_in, const int* in_sizes, int n_in,
                              void* d_out, int out_size, void* d_ws, size_t ws_size,
                              hipStream_t stream) {
    const float* cam = (const float*)d_in[0];
    const float* ray = (const float*)d_in[1];
    int B = in_sizes[0] / 3;
    int R = in_sizes[1] / 3;
    int N = R / B;
    int threads = 256;
    int blocks = (R + threads - 1) / threads;
    raytrace_kernel<<<blocks, threads, 0, stream>>>(cam, ray, (float*)d_out, N, R);
}